// Round 1
// baseline (2954.923 us; speedup 1.0000x reference)
//
#include <hip/hip_runtime.h>
#include <math.h>

#define NTOK   16384
#define DDIM   256
#define KCODE  16384
#define HWD    1024        // H*W per batch image
#define CHW    262144      // 256*1024 floats per batch
#define NTILE  128         // number of 128-code tiles
#define TILEK  128
#define KSPLIT 4
#define MARGIN 7.0e-5f     // 2 fp32 grid steps @256 + slack

// ---------------- kernel A: zz[n] = fl32( sum_d z[n,d]^2 ) ----------------
__global__ __launch_bounds__(256) void k_zz(const float* __restrict__ z,
                                            float* __restrict__ zz) {
  __shared__ float zt[32][64];
  const int tg = blockIdx.x;            // 256 groups of 64 tokens
  const int n0 = tg * 64;
  const int b = n0 >> 10, hw0 = n0 & 1023;
  const float* zb = z + (size_t)b * CHW + hw0;
  const int tid = threadIdx.x;
  double s = 0.0;
  for (int dc = 0; dc < 8; ++dc) {
    __syncthreads();
    for (int i = tid; i < 2048; i += 256) {
      int dd = i >> 6, t = i & 63;
      zt[dd][t] = zb[(size_t)(dc * 32 + dd) * HWD + t];
    }
    __syncthreads();
    if (tid < 64) {
      #pragma unroll
      for (int dd = 0; dd < 32; ++dd) { float v = zt[dd][tid]; s += (double)(v * v); }
    }
  }
  if (tid < 64) zz[n0 + tid] = (float)s;
}

// ---------------- kernel B: ee[k] = fl32( sum_d emb[k,d]^2 ) ----------------
__global__ __launch_bounds__(256) void k_ee(const float* __restrict__ emb,
                                            float* __restrict__ ee) {
  __shared__ float et[64][33];
  const int kg = blockIdx.x;            // 256 groups of 64 codes
  const int k0 = kg * 64;
  const int tid = threadIdx.x;
  double s = 0.0;
  for (int dc = 0; dc < 8; ++dc) {
    __syncthreads();
    for (int i = tid; i < 2048; i += 256) {
      int kk = i >> 5, dd = i & 31;
      et[kk][dd] = emb[(size_t)(k0 + kk) * DDIM + dc * 32 + dd];
    }
    __syncthreads();
    if (tid < 64) {
      #pragma unroll
      for (int dd = 0; dd < 32; ++dd) { float v = et[tid][dd]; s += (double)(v * v); }
    }
  }
  if (tid < 64) ee[k0 + tid] = (float)s;
}

// ---------------- kernel C: phase-1 distances, per-(token,tile) min ----------------
// block: 256 thr = 16 tcol x 16 trow; 64 tokens x 128 codes, thread tile 4x8.
// grid: (256 token-groups, KSPLIT); each block does 128/KSPLIT tiles.
__global__ __launch_bounds__(256, 4) void k_dist(
    const float* __restrict__ z, const float* __restrict__ emb,
    const float* __restrict__ zz, const float* __restrict__ ee,
    float* __restrict__ tilemin) {
  __shared__ float zt[32][64];        // [d][token]
  __shared__ float et[32][132];       // [d][code], pad 132 keeps 16B align + spreads banks
  __shared__ float red[64][17];       // [token][tcol] partial mins
  const int tg = blockIdx.x;
  const int ks = blockIdx.y;
  const int n0 = tg * 64;
  const int b = n0 >> 10, hw0 = n0 & 1023;
  const float* zb = z + (size_t)b * CHW + hw0;
  const int tid = threadIdx.x;
  const int tcol = tid & 15, trow = tid >> 4;
  float zzr[4];
  #pragma unroll
  for (int i = 0; i < 4; ++i) zzr[i] = zz[n0 + trow * 4 + i];

  for (int ktl = 0; ktl < NTILE / KSPLIT; ++ktl) {
    const int ktg = ks * (NTILE / KSPLIT) + ktl;
    const int kbase = ktg * TILEK;
    float acc[4][8];
    #pragma unroll
    for (int i = 0; i < 4; ++i)
      #pragma unroll
      for (int j = 0; j < 8; ++j) acc[i][j] = 0.0f;

    for (int dc = 0; dc < 8; ++dc) {
      __syncthreads();
      { // stage z: 32 d x 64 tok (float4, coalesced)
        int i4 = tid;
        #pragma unroll
        for (int r = 0; r < 2; ++r, i4 += 256) {
          int dd = i4 >> 4, t4 = i4 & 15;
          float4 v = *(const float4*)(zb + (size_t)(dc * 32 + dd) * HWD + t4 * 4);
          *(float4*)&zt[dd][t4 * 4] = v;
        }
      }
      { // stage e: 32 d x 128 codes (scalar, coalesced along d)
        int i = tid;
        #pragma unroll
        for (int r = 0; r < 16; ++r, i += 256) {
          int dd = i & 31, kk = i >> 5;
          et[dd][kk] = emb[(size_t)(kbase + kk) * DDIM + dc * 32 + dd];
        }
      }
      __syncthreads();
      #pragma unroll
      for (int dd = 0; dd < 32; ++dd) {
        float4 zf = *(const float4*)&zt[dd][trow * 4];
        float4 e0 = *(const float4*)&et[dd][tcol * 8];
        float4 e1 = *(const float4*)&et[dd][tcol * 8 + 4];
        float zv[4]  = {zf.x, zf.y, zf.z, zf.w};
        float evv[8] = {e0.x, e0.y, e0.z, e0.w, e1.x, e1.y, e1.z, e1.w};
        #pragma unroll
        for (int i = 0; i < 4; ++i)
          #pragma unroll
          for (int j = 0; j < 8; ++j)
            acc[i][j] = fmaf(zv[i], evv[j], acc[i][j]);
      }
    }
    // epilogue: d = (zz+ee) - 2*acc ; per-thread min over 8 codes
    float eev[8];
    *(float4*)&eev[0] = *(const float4*)(ee + kbase + tcol * 8);
    *(float4*)&eev[4] = *(const float4*)(ee + kbase + tcol * 8 + 4);
    float emin[4] = {3.0e38f, 3.0e38f, 3.0e38f, 3.0e38f};
    #pragma unroll
    for (int i = 0; i < 4; ++i) {
      #pragma unroll
      for (int j = 0; j < 8; ++j) {
        float s = zzr[i] + eev[j];
        float d = s - 2.0f * acc[i][j];
        emin[i] = fminf(emin[i], d);
      }
    }
    __syncthreads();
    #pragma unroll
    for (int i = 0; i < 4; ++i) red[trow * 4 + i][tcol] = emin[i];
    __syncthreads();
    if (tid < 64) {
      float m = red[tid][0];
      #pragma unroll
      for (int c = 1; c < 16; ++c) m = fminf(m, red[tid][c]);
      tilemin[(size_t)(n0 + tid) * NTILE + ktg] = m;
    }
  }
}

// ---------------- kernel P2: exact re-check of candidate tiles, argmin ----------------
__global__ __launch_bounds__(256) void k_pick(
    const float* __restrict__ z, const float* __restrict__ emb,
    const float* __restrict__ zz, const float* __restrict__ ee,
    const float* __restrict__ tilemin, int* __restrict__ idx,
    float* __restrict__ out_idxf) {
  __shared__ float zrow[256];
  __shared__ float tm[128];
  __shared__ float gminS;
  __shared__ float rbd[4];
  __shared__ int   rbk[4];
  const int n = blockIdx.x;
  const int b = n >> 10, hw = n & 1023;
  const int tid = threadIdx.x;
  zrow[tid] = z[(size_t)b * CHW + (size_t)tid * HWD + hw];
  if (tid < 128) tm[tid] = tilemin[(size_t)n * NTILE + tid];
  __syncthreads();
  if (tid < 64) {
    float m = fminf(tm[tid], tm[tid + 64]);
    #pragma unroll
    for (int o = 32; o; o >>= 1) m = fminf(m, __shfl_xor(m, o, 64));
    if (tid == 0) gminS = m;
  }
  __syncthreads();
  const float thr = gminS + MARGIN;
  const float zzn = zz[n];
  const int wid = tid >> 6, lane = tid & 63;
  float bd = 3.0e38f;
  int bk = 0x7fffffff;
  for (int t = 0; t < NTILE; ++t) {
    if (tm[t] > thr) continue;            // uniform branch
    const int kbase = t * TILEK;
    for (int c = wid; c < TILEK; c += 4) { // wave's codes ascending
      const int k = kbase + c;
      const float* er = emb + (size_t)k * DDIM;
      double s = 0.0;
      #pragma unroll
      for (int j = 0; j < 4; ++j)
        s += (double)zrow[lane + 64 * j] * (double)er[lane + 64 * j];
      #pragma unroll
      for (int o = 32; o; o >>= 1) s += __shfl_xor(s, o, 64);
      const float mm = (float)s;                        // exact dot -> one fp32 rounding
      const float d = (zzn + ee[k]) - 2.0f * mm;        // replicate ref quantization
      if (d < bd) { bd = d; bk = k; }                   // strict < => first index wins
    }
  }
  if (lane == 0) { rbd[wid] = bd; rbk[wid] = bk; }
  __syncthreads();
  if (tid == 0) {
    float d0 = rbd[0]; int k0 = rbk[0];
    #pragma unroll
    for (int w = 1; w < 4; ++w) {
      float dw = rbd[w]; int kw = rbk[w];
      if (dw < d0 || (dw == d0 && kw < k0)) { d0 = dw; k0 = kw; }
    }
    idx[n] = k0;
    out_idxf[n] = (float)k0;
  }
}

// ---------------- kernel D: scatter z_q, loss partial, counts ----------------
__global__ __launch_bounds__(256) void k_scatter(
    const float* __restrict__ z, const float* __restrict__ emb,
    const int* __restrict__ idx, float* __restrict__ out_zq,
    int* __restrict__ counts, double* __restrict__ sums) {
  const int n = blockIdx.x;
  const int b = n >> 10, hw = n & 1023;
  const int tid = threadIdx.x;
  const int k = idx[n];
  const float v = emb[(size_t)k * DDIM + tid];
  const size_t o = (size_t)b * CHW + (size_t)tid * HWD + hw;
  const float diff = v - z[o];
  out_zq[o] = v;                              // z_q_st == z_q numerically
  double s = (double)diff * (double)diff;
  #pragma unroll
  for (int o2 = 32; o2; o2 >>= 1) s += __shfl_xor(s, o2, 64);
  __shared__ double w4[4];
  const int wid = tid >> 6, lane = tid & 63;
  if (lane == 0) w4[wid] = s;
  __syncthreads();
  if (tid == 0) {
    atomicAdd(&sums[0], w4[0] + w4[1] + w4[2] + w4[3]);
    atomicAdd(&counts[k], 1);
  }
}

// ---------------- kernel E: entropy partial from counts ----------------
__global__ __launch_bounds__(256) void k_hist(const int* __restrict__ counts,
                                              double* __restrict__ sums) {
  const int i = blockIdx.x * 256 + threadIdx.x;
  const float em = (float)counts[i] * (1.0f / 16384.0f);
  const float term = em * logf(em + 1e-10f);
  double s = (double)term;
  #pragma unroll
  for (int o = 32; o; o >>= 1) s += __shfl_xor(s, o, 64);
  __shared__ double w4[4];
  const int wid = threadIdx.x >> 6, lane = threadIdx.x & 63;
  if (lane == 0) w4[wid] = s;
  __syncthreads();
  if (threadIdx.x == 0) atomicAdd(&sums[1], w4[0] + w4[1] + w4[2] + w4[3]);
}

// ---------------- kernel F: finals ----------------
__global__ void k_final(const double* __restrict__ sums,
                        float* __restrict__ out_loss,
                        float* __restrict__ out_perp) {
  if (threadIdx.x == 0) {
    out_loss[0] = (float)(1.25 * sums[0] / 4194304.0);  // (1+BETA)*mean
    out_perp[0] = (float)exp(-sums[1]);
  }
}

extern "C" void kernel_launch(void* const* d_in, const int* in_sizes, int n_in,
                              void* d_out, int out_size, void* d_ws, size_t ws_size,
                              hipStream_t stream) {
  const float* z   = (const float*)d_in[0];   // [16,256,32,32]
  const float* emb = (const float*)d_in[1];   // [16384,256]
  float* out      = (float*)d_out;
  float* out_zq   = out;                      // 4194304
  float* out_loss = out + 4194304;
  float* out_perp = out + 4194305;
  float* out_idxf = out + 4194306;            // 16384 (idx as float)

  char* ws = (char*)d_ws;
  float*  ee      = (float*)ws;                                   // 64KB
  float*  zz      = (float*)(ws + 65536);                         // 64KB
  float*  tilemin = (float*)(ws + 131072);                        // 8MB
  int*    idx     = (int*)  (ws + 131072 + 8388608);              // 64KB
  int*    counts  = (int*)  (ws + 131072 + 8388608 + 65536);      // 64KB
  double* sums    = (double*)(ws + 131072 + 8388608 + 131072);    // 16B

  // zero counts + the two accumulators (contiguous region) every launch
  hipMemsetAsync(counts, 0, 65536 + 16, stream);

  k_zz  <<<256, 256, 0, stream>>>(z, zz);
  k_ee  <<<256, 256, 0, stream>>>(emb, ee);
  k_dist<<<dim3(256, KSPLIT), 256, 0, stream>>>(z, emb, zz, ee, tilemin);
  k_pick<<<NTOK, 256, 0, stream>>>(z, emb, zz, ee, tilemin, idx, out_idxf);
  k_scatter<<<NTOK, 256, 0, stream>>>(z, emb, idx, out_zq, counts, sums);
  k_hist<<<64, 256, 0, stream>>>(counts, sums);
  k_final<<<1, 64, 0, stream>>>(sums, out_loss, out_perp);
}

// Round 2
// 1052.311 us; speedup vs baseline: 2.8080x; 2.8080x over previous
//
#include <hip/hip_runtime.h>
#include <math.h>

#define NTOK   16384
#define DDIM   256
#define KCODE  16384
#define HWD    1024        // H*W per batch image
#define CHW    262144      // 256*1024 floats per batch
#define NTILE  128         // number of 128-code tiles
#define TILEK  128
#define MARGIN 1.6e-4f     // bf16 phase-1 error (8 sigma) + ref d-grid quantization + ee span

// ws layout (bytes)
#define WS_ABF   0u          // 8 MB  bf16 token images [128 tiles][4 chunks][16KB swizzled image]
#define WS_BBF   8388608u    // 8 MB  bf16 code  images
#define WS_TMIN  16777216u   // 8 MB  fp32 tilemin, TRANSPOSED: [tile][token]
#define WS_EE    25165824u   // 64KB
#define WS_ZZ    25231360u   // 64KB
#define WS_IDX   25296896u   // 64KB
#define WS_CNT   25362432u   // 64KB
#define WS_SUM   25427968u   // 16B   (contiguous after counts)

typedef __attribute__((ext_vector_type(8))) short  s8b;    // 8 bf16 (4 VGPR)
typedef __attribute__((ext_vector_type(8))) unsigned short us8;
typedef __attribute__((ext_vector_type(4))) float  f32x4;

__device__ __forceinline__ unsigned short f2bf(float f) {
  unsigned int u = __float_as_uint(f);
  return (unsigned short)((u + 0x7fffu + ((u >> 16) & 1u)) >> 16);  // RNE
}

// ---------------- kernel A: zz[n] = fl32( sum_d z[n,d]^2 ) ----------------
__global__ __launch_bounds__(256) void k_zz(const float* __restrict__ z,
                                            float* __restrict__ zz) {
  __shared__ float zt[32][64];
  const int tg = blockIdx.x;            // 256 groups of 64 tokens
  const int n0 = tg * 64;
  const int b = n0 >> 10, hw0 = n0 & 1023;
  const float* zb = z + (size_t)b * CHW + hw0;
  const int tid = threadIdx.x;
  double s = 0.0;
  for (int dc = 0; dc < 8; ++dc) {
    __syncthreads();
    for (int i = tid; i < 2048; i += 256) {
      int dd = i >> 6, t = i & 63;
      zt[dd][t] = zb[(size_t)(dc * 32 + dd) * HWD + t];
    }
    __syncthreads();
    if (tid < 64) {
      #pragma unroll
      for (int dd = 0; dd < 32; ++dd) { float v = zt[dd][tid]; s += (double)(v * v); }
    }
  }
  if (tid < 64) zz[n0 + tid] = (float)s;
}

// ---------------- kernel B: ee[k] = fl32( sum_d emb[k,d]^2 ) ----------------
__global__ __launch_bounds__(256) void k_ee(const float* __restrict__ emb,
                                            float* __restrict__ ee) {
  __shared__ float et[64][33];
  const int kg = blockIdx.x;            // 256 groups of 64 codes
  const int k0 = kg * 64;
  const int tid = threadIdx.x;
  double s = 0.0;
  for (int dc = 0; dc < 8; ++dc) {
    __syncthreads();
    for (int i = tid; i < 2048; i += 256) {
      int kk = i >> 5, dd = i & 31;
      et[kk][dd] = emb[(size_t)(k0 + kk) * DDIM + dc * 32 + dd];
    }
    __syncthreads();
    if (tid < 64) {
      #pragma unroll
      for (int dd = 0; dd < 32; ++dd) { float v = et[tid][dd]; s += (double)(v * v); }
    }
  }
  if (tid < 64) ee[k0 + tid] = (float)s;
}

// ---------------- conversion: z (NCHW) -> bf16 swizzled token images ----------------
// image layout per (tile, chunk): phys_byte(row,k) = ((row*128 + (k>>3)*16) ^ ((row&7)<<4)) + (k&7)*2
__global__ __launch_bounds__(256) void k_cvtA(const float* __restrict__ z,
                                              unsigned short* __restrict__ Abf) {
  const int g = blockIdx.x * 256 + threadIdx.x;   // 65536 threads
  const int n = g & 16383, chunk = g >> 14;
  const int b = n >> 10, hw = n & 1023;
  const float* zp = z + (size_t)b * CHW + hw;
  const int row = n & 127, tile = n >> 7;
  char* dst = (char*)Abf + (size_t)tile * 65536 + (size_t)chunk * 16384;
  const int rowoff = row * 128, sw = (row & 7) << 4;
  #pragma unroll
  for (int kb = 0; kb < 8; ++kb) {
    us8 v;
    #pragma unroll
    for (int j = 0; j < 8; ++j) {
      const int d = chunk * 64 + kb * 8 + j;
      v[j] = f2bf(zp[(size_t)d * HWD]);
    }
    *(us8*)(dst + ((rowoff + kb * 16) ^ sw)) = v;
  }
}

// ---------------- conversion: emb -> bf16 swizzled code images ----------------
__global__ __launch_bounds__(256) void k_cvtB(const float* __restrict__ emb,
                                              unsigned short* __restrict__ Bbf) {
  const int g = blockIdx.x * 256 + threadIdx.x;   // 65536 threads
  const int code = g & 16383, chunk = g >> 14;
  const float* ep = emb + (size_t)code * DDIM + chunk * 64;
  const int row = code & 127, tile = code >> 7;
  char* dst = (char*)Bbf + (size_t)tile * 65536 + (size_t)chunk * 16384;
  const int rowoff = row * 128, sw = (row & 7) << 4;
  #pragma unroll
  for (int kb = 0; kb < 8; ++kb) {
    us8 v;
    #pragma unroll
    for (int j = 0; j < 8; ++j) v[j] = f2bf(ep[kb * 8 + j]);
    *(us8*)(dst + ((rowoff + kb * 16) ^ sw)) = v;
  }
}

// ---------------- phase-1: MFMA dot-max per (token, 128-code tile) ----------------
// 16384 blocks = 128 token-tiles x 128 code-tiles. 256 thr = 4 waves (2x2),
// wave computes 64x64 via 4x4 fragments of mfma_f32_16x16x32_bf16, K=256 in 4 BK=64 steps.
__global__ __launch_bounds__(256, 3) void k_mdist(
    const unsigned short* __restrict__ Abf, const unsigned short* __restrict__ Bbf,
    float* __restrict__ tilemin) {
  __shared__ __attribute__((aligned(16))) unsigned short ldsA[8192];  // 16KB image
  __shared__ __attribute__((aligned(16))) unsigned short ldsB[8192];
  __shared__ float red[128][2];
  const int raw = blockIdx.x;
  // XCD chunking (16384 % 8 == 0 -> simple bijective) + 16x16 supertiles for L2
  const int swz = (raw & 7) * 2048 + (raw >> 3);
  const int sid = swz >> 8, lid = swz & 255;
  const int ttile = (sid >> 3) * 16 + (lid >> 4);
  const int ctile = (sid & 7) * 16 + (lid & 15);
  const int tid = threadIdx.x;
  const int w = tid >> 6, lane = tid & 63;
  const int wr = w >> 1, wc = w & 1;
  const int fr = lane & 15, fq = lane >> 4;
  const char* abase = (const char*)Abf + (size_t)ttile * 65536;
  const char* bbase = (const char*)Bbf + (size_t)ctile * 65536;

  f32x4 acc[4][4];
  #pragma unroll
  for (int m = 0; m < 4; ++m)
    #pragma unroll
    for (int n = 0; n < 4; ++n) acc[m][n] = (f32x4)0.0f;

  int aoff[4][2], boff[4][2];
  #pragma unroll
  for (int m = 0; m < 4; ++m)
    #pragma unroll
    for (int s = 0; s < 2; ++s) {
      const int row  = wr * 64 + m * 16 + fr;
      const int code = wc * 64 + m * 16 + fr;
      aoff[m][s] = (row  * 128 + (s * 4 + fq) * 16) ^ ((row  & 7) << 4);
      boff[m][s] = (code * 128 + (s * 4 + fq) * 16) ^ ((code & 7) << 4);
    }

  for (int it = 0; it < 4; ++it) {
    __syncthreads();   // prev iter's ds_reads done before overwrite
    {
      const char* ga = abase + it * 16384 + w * 1024 + lane * 16;
      const char* gb = bbase + it * 16384 + w * 1024 + lane * 16;
      #pragma unroll
      for (int r = 0; r < 4; ++r) {
        __builtin_amdgcn_global_load_lds(
            (const __attribute__((address_space(1))) void*)(ga + r * 4096),
            (__attribute__((address_space(3))) void*)((char*)ldsA + (r * 4 + w) * 1024),
            16, 0, 0);
        __builtin_amdgcn_global_load_lds(
            (const __attribute__((address_space(1))) void*)(gb + r * 4096),
            (__attribute__((address_space(3))) void*)((char*)ldsB + (r * 4 + w) * 1024),
            16, 0, 0);
      }
    }
    __syncthreads();   // drains vmcnt(0): staged data visible
    #pragma unroll
    for (int s = 0; s < 2; ++s) {
      s8b a[4], b[4];
      #pragma unroll
      for (int m = 0; m < 4; ++m) a[m] = *(const s8b*)((const char*)ldsA + aoff[m][s]);
      #pragma unroll
      for (int n = 0; n < 4; ++n) b[n] = *(const s8b*)((const char*)ldsB + boff[n][s]);
      #pragma unroll
      for (int m = 0; m < 4; ++m)
        #pragma unroll
        for (int n = 0; n < 4; ++n)
          acc[m][n] = __builtin_amdgcn_mfma_f32_16x16x32_bf16(a[m], b[n], acc[m][n], 0, 0, 0);
    }
  }

  // epilogue: per-token max over this block's 128 codes -> tilemin = -2*max
  #pragma unroll
  for (int m = 0; m < 4; ++m) {
    #pragma unroll
    for (int j = 0; j < 4; ++j) {
      float v = fmaxf(fmaxf(acc[m][0][j], acc[m][1][j]),
                      fmaxf(acc[m][2][j], acc[m][3][j]));
      #pragma unroll
      for (int msk = 1; msk < 16; msk <<= 1)
        v = fmaxf(v, __shfl_xor(v, msk, 64));
      if (fr == 0) red[wr * 64 + m * 16 + fq * 4 + j][wc] = v;
    }
  }
  __syncthreads();
  if (tid < 128)
    tilemin[(size_t)ctile * NTOK + ttile * 128 + tid] =
        -2.0f * fmaxf(red[tid][0], red[tid][1]);
}

// ---------------- phase-2: exact re-check of candidate tiles, argmin ----------------
__global__ __launch_bounds__(256) void k_pick(
    const float* __restrict__ z, const float* __restrict__ emb,
    const float* __restrict__ zz, const float* __restrict__ ee,
    const float* __restrict__ tilemin, int* __restrict__ idx,
    float* __restrict__ out_idxf) {
  __shared__ float zrow[256];
  __shared__ float tm[128];
  __shared__ float gminS;
  __shared__ float rbd[4];
  __shared__ int   rbk[4];
  const int n = blockIdx.x;
  const int b = n >> 10, hw = n & 1023;
  const int tid = threadIdx.x;
  zrow[tid] = z[(size_t)b * CHW + (size_t)tid * HWD + hw];
  if (tid < 128) tm[tid] = tilemin[(size_t)tid * NTOK + n];   // transposed layout
  __syncthreads();
  if (tid < 64) {
    float m = fminf(tm[tid], tm[tid + 64]);
    #pragma unroll
    for (int o = 32; o; o >>= 1) m = fminf(m, __shfl_xor(m, o, 64));
    if (tid == 0) gminS = m;
  }
  __syncthreads();
  const float thr = gminS + MARGIN;
  const float zzn = zz[n];
  const int wid = tid >> 6, lane = tid & 63;
  float bd = 3.0e38f;
  int bk = 0x7fffffff;
  for (int t = 0; t < NTILE; ++t) {
    if (tm[t] > thr) continue;            // uniform branch
    const int kbase = t * TILEK;
    for (int c = wid; c < TILEK; c += 4) { // wave's codes ascending
      const int k = kbase + c;
      const float* er = emb + (size_t)k * DDIM;
      double s = 0.0;
      #pragma unroll
      for (int j = 0; j < 4; ++j)
        s += (double)zrow[lane + 64 * j] * (double)er[lane + 64 * j];
      #pragma unroll
      for (int o = 32; o; o >>= 1) s += __shfl_xor(s, o, 64);
      const float mm = (float)s;                        // exact dot -> one fp32 rounding
      const float d = (zzn + ee[k]) - 2.0f * mm;        // replicate ref quantization
      if (d < bd) { bd = d; bk = k; }                   // strict < => first index wins
    }
  }
  if (lane == 0) { rbd[wid] = bd; rbk[wid] = bk; }
  __syncthreads();
  if (tid == 0) {
    float d0 = rbd[0]; int k0 = rbk[0];
    #pragma unroll
    for (int w = 1; w < 4; ++w) {
      float dw = rbd[w]; int kw = rbk[w];
      if (dw < d0 || (dw == d0 && kw < k0)) { d0 = dw; k0 = kw; }
    }
    idx[n] = k0;
    out_idxf[n] = (float)k0;
  }
}

// ---------------- scatter z_q, loss partial, counts ----------------
__global__ __launch_bounds__(256) void k_scatter(
    const float* __restrict__ z, const float* __restrict__ emb,
    const int* __restrict__ idx, float* __restrict__ out_zq,
    int* __restrict__ counts, double* __restrict__ sums) {
  const int n = blockIdx.x;
  const int b = n >> 10, hw = n & 1023;
  const int tid = threadIdx.x;
  const int k = idx[n];
  const float v = emb[(size_t)k * DDIM + tid];
  const size_t o = (size_t)b * CHW + (size_t)tid * HWD + hw;
  const float diff = v - z[o];
  out_zq[o] = v;                              // z_q_st == z_q numerically
  double s = (double)diff * (double)diff;
  #pragma unroll
  for (int o2 = 32; o2; o2 >>= 1) s += __shfl_xor(s, o2, 64);
  __shared__ double w4[4];
  const int wid = tid >> 6, lane = tid & 63;
  if (lane == 0) w4[wid] = s;
  __syncthreads();
  if (tid == 0) {
    atomicAdd(&sums[0], w4[0] + w4[1] + w4[2] + w4[3]);
    atomicAdd(&counts[k], 1);
  }
}

// ---------------- entropy partial from counts ----------------
__global__ __launch_bounds__(256) void k_hist(const int* __restrict__ counts,
                                              double* __restrict__ sums) {
  const int i = blockIdx.x * 256 + threadIdx.x;
  const float em = (float)counts[i] * (1.0f / 16384.0f);
  const float term = em * logf(em + 1e-10f);
  double s = (double)term;
  #pragma unroll
  for (int o = 32; o; o >>= 1) s += __shfl_xor(s, o, 64);
  __shared__ double w4[4];
  const int wid = threadIdx.x >> 6, lane = threadIdx.x & 63;
  if (lane == 0) w4[wid] = s;
  __syncthreads();
  if (threadIdx.x == 0) atomicAdd(&sums[1], w4[0] + w4[1] + w4[2] + w4[3]);
}

// ---------------- finals ----------------
__global__ void k_final(const double* __restrict__ sums,
                        float* __restrict__ out_loss,
                        float* __restrict__ out_perp) {
  if (threadIdx.x == 0) {
    out_loss[0] = (float)(1.25 * sums[0] / 4194304.0);  // (1+BETA)*mean
    out_perp[0] = (float)exp(-sums[1]);
  }
}

extern "C" void kernel_launch(void* const* d_in, const int* in_sizes, int n_in,
                              void* d_out, int out_size, void* d_ws, size_t ws_size,
                              hipStream_t stream) {
  const float* z   = (const float*)d_in[0];   // [16,256,32,32]
  const float* emb = (const float*)d_in[1];   // [16384,256]
  float* out      = (float*)d_out;
  float* out_zq   = out;                      // 4194304
  float* out_loss = out + 4194304;
  float* out_perp = out + 4194305;
  float* out_idxf = out + 4194306;            // 16384 (idx as float)

  char* ws = (char*)d_ws;
  unsigned short* Abf = (unsigned short*)(ws + WS_ABF);
  unsigned short* Bbf = (unsigned short*)(ws + WS_BBF);
  float*  tilemin = (float*)(ws + WS_TMIN);
  float*  ee      = (float*)(ws + WS_EE);
  float*  zz      = (float*)(ws + WS_ZZ);
  int*    idx     = (int*)  (ws + WS_IDX);
  int*    counts  = (int*)  (ws + WS_CNT);
  double* sums    = (double*)(ws + WS_SUM);

  hipMemsetAsync(counts, 0, 65536 + 16, stream);

  k_cvtA <<<256, 256, 0, stream>>>(z, Abf);
  k_cvtB <<<256, 256, 0, stream>>>(emb, Bbf);
  k_mdist<<<16384, 256, 0, stream>>>(Abf, Bbf, tilemin);
  k_zz   <<<256, 256, 0, stream>>>(z, zz);
  k_ee   <<<256, 256, 0, stream>>>(emb, ee);
  k_pick <<<NTOK, 256, 0, stream>>>(z, emb, zz, ee, tilemin, idx, out_idxf);
  k_scatter<<<NTOK, 256, 0, stream>>>(z, emb, idx, out_zq, counts, sums);
  k_hist <<<64, 256, 0, stream>>>(counts, sums);
  k_final<<<1, 64, 0, stream>>>(sums, out_loss, out_perp);
}

// Round 3
// 415.333 us; speedup vs baseline: 7.1146x; 2.5337x over previous
//
#include <hip/hip_runtime.h>
#include <math.h>

#define NTOK   16384
#define DDIM   256
#define KCODE  16384
#define HWD    1024        // H*W per batch image
#define CHW    262144      // 256*1024 floats per batch
#define MARGIN 1.6e-4f     // bf16 phase-1 error (8 sigma) + ref d-grid + ee span + fp16 tm quant

// ws layout (bytes)
#define WS_ABF   0u          // 8 MB  bf16 token images [128 tiles][4 chunks][16KB swizzled image]
#define WS_BBF   8388608u    // 8 MB  bf16 code  images
#define WS_SUBT  16777216u   // 16 MB fp16 subtile mins: [n>>6][n&63][512 subtiles]
#define WS_EE    33554432u   // 64KB
#define WS_ZZ    33619968u   // 64KB
#define WS_IDX   33685504u   // 64KB
#define WS_CNT   33751040u   // 64KB
#define WS_SUM   33816576u   // 16B (contiguous after counts)

typedef __attribute__((ext_vector_type(8))) short  s8b;    // 8 bf16 (4 VGPR)
typedef __attribute__((ext_vector_type(8))) unsigned short us8;
typedef __attribute__((ext_vector_type(4))) float  f32x4;
typedef __attribute__((ext_vector_type(4))) _Float16 h4;

__device__ __forceinline__ unsigned short f2bf(float f) {
  unsigned int u = __float_as_uint(f);
  return (unsigned short)((u + 0x7fffu + ((u >> 16) & 1u)) >> 16);  // RNE
}

// ---------------- kernel A: zz[n] = fl32( sum_d z[n,d]^2 ) ----------------
__global__ __launch_bounds__(256) void k_zz(const float* __restrict__ z,
                                            float* __restrict__ zz) {
  __shared__ float zt[32][64];
  const int tg = blockIdx.x;            // 256 groups of 64 tokens
  const int n0 = tg * 64;
  const int b = n0 >> 10, hw0 = n0 & 1023;
  const float* zb = z + (size_t)b * CHW + hw0;
  const int tid = threadIdx.x;
  double s = 0.0;
  for (int dc = 0; dc < 8; ++dc) {
    __syncthreads();
    for (int i = tid; i < 2048; i += 256) {
      int dd = i >> 6, t = i & 63;
      zt[dd][t] = zb[(size_t)(dc * 32 + dd) * HWD + t];
    }
    __syncthreads();
    if (tid < 64) {
      #pragma unroll
      for (int dd = 0; dd < 32; ++dd) { float v = zt[dd][tid]; s += (double)(v * v); }
    }
  }
  if (tid < 64) zz[n0 + tid] = (float)s;
}

// ---------------- kernel B: ee[k] = fl32( sum_d emb[k,d]^2 ) ----------------
__global__ __launch_bounds__(256) void k_ee(const float* __restrict__ emb,
                                            float* __restrict__ ee) {
  __shared__ float et[64][33];
  const int kg = blockIdx.x;            // 256 groups of 64 codes
  const int k0 = kg * 64;
  const int tid = threadIdx.x;
  double s = 0.0;
  for (int dc = 0; dc < 8; ++dc) {
    __syncthreads();
    for (int i = tid; i < 2048; i += 256) {
      int kk = i >> 5, dd = i & 31;
      et[kk][dd] = emb[(size_t)(k0 + kk) * DDIM + dc * 32 + dd];
    }
    __syncthreads();
    if (tid < 64) {
      #pragma unroll
      for (int dd = 0; dd < 32; ++dd) { float v = et[tid][dd]; s += (double)(v * v); }
    }
  }
  if (tid < 64) ee[k0 + tid] = (float)s;
}

// ---------------- conversion: z (NCHW) -> bf16 swizzled token images ----------------
// image layout per (tile, chunk): phys_byte(row,k) = ((row*128 + (k>>3)*16) ^ ((row&7)<<4)) + (k&7)*2
__global__ __launch_bounds__(256) void k_cvtA(const float* __restrict__ z,
                                              unsigned short* __restrict__ Abf) {
  const int g = blockIdx.x * 256 + threadIdx.x;   // 65536 threads
  const int n = g & 16383, chunk = g >> 14;
  const int b = n >> 10, hw = n & 1023;
  const float* zp = z + (size_t)b * CHW + hw;
  const int row = n & 127, tile = n >> 7;
  char* dst = (char*)Abf + (size_t)tile * 65536 + (size_t)chunk * 16384;
  const int rowoff = row * 128, sw = (row & 7) << 4;
  #pragma unroll
  for (int kb = 0; kb < 8; ++kb) {
    us8 v;
    #pragma unroll
    for (int j = 0; j < 8; ++j) {
      const int d = chunk * 64 + kb * 8 + j;
      v[j] = f2bf(zp[(size_t)d * HWD]);
    }
    *(us8*)(dst + ((rowoff + kb * 16) ^ sw)) = v;
  }
}

// ---------------- conversion: emb -> bf16 swizzled code images ----------------
__global__ __launch_bounds__(256) void k_cvtB(const float* __restrict__ emb,
                                              unsigned short* __restrict__ Bbf) {
  const int g = blockIdx.x * 256 + threadIdx.x;   // 65536 threads
  const int code = g & 16383, chunk = g >> 14;
  const float* ep = emb + (size_t)code * DDIM + chunk * 64;
  const int row = code & 127, tile = code >> 7;
  char* dst = (char*)Bbf + (size_t)tile * 65536 + (size_t)chunk * 16384;
  const int rowoff = row * 128, sw = (row & 7) << 4;
  #pragma unroll
  for (int kb = 0; kb < 8; ++kb) {
    us8 v;
    #pragma unroll
    for (int j = 0; j < 8; ++j) v[j] = f2bf(ep[kb * 8 + j]);
    *(us8*)(dst + ((rowoff + kb * 16) ^ sw)) = v;
  }
}

// ---------------- phase-1: MFMA dot-max per (token, 32-code subtile) ----------------
// 16384 blocks = 128 token-tiles x 128 code-tiles. 256 thr = 4 waves (2x2),
// wave computes 64x64 via 4x4 fragments of mfma_f32_16x16x32_bf16, K=256 in 4 BK=64 steps.
__global__ __launch_bounds__(256, 4) void k_mdist(
    const unsigned short* __restrict__ Abf, const unsigned short* __restrict__ Bbf,
    _Float16* __restrict__ subt) {
  __shared__ __attribute__((aligned(16))) unsigned short ldsA[8192];  // 16KB image
  __shared__ __attribute__((aligned(16))) unsigned short ldsB[8192];
  __shared__ float red[128][4];
  const int raw = blockIdx.x;
  // XCD chunking (16384 % 8 == 0 -> bijective) + 16x16 supertiles for L2
  const int swz = (raw & 7) * 2048 + (raw >> 3);
  const int sid = swz >> 8, lid = swz & 255;
  const int ttile = (sid >> 3) * 16 + (lid >> 4);
  const int ctile = (sid & 7) * 16 + (lid & 15);
  const int tid = threadIdx.x;
  const int w = tid >> 6, lane = tid & 63;
  const int wr = w >> 1, wc = w & 1;
  const int fr = lane & 15, fq = lane >> 4;
  const char* abase = (const char*)Abf + (size_t)ttile * 65536;
  const char* bbase = (const char*)Bbf + (size_t)ctile * 65536;

  f32x4 acc[4][4];
  #pragma unroll
  for (int m = 0; m < 4; ++m)
    #pragma unroll
    for (int n = 0; n < 4; ++n) acc[m][n] = (f32x4)0.0f;

  int aoff[4][2], boff[4][2];
  #pragma unroll
  for (int m = 0; m < 4; ++m)
    #pragma unroll
    for (int s = 0; s < 2; ++s) {
      const int row  = wr * 64 + m * 16 + fr;
      const int code = wc * 64 + m * 16 + fr;
      aoff[m][s] = (row  * 128 + (s * 4 + fq) * 16) ^ ((row  & 7) << 4);
      boff[m][s] = (code * 128 + (s * 4 + fq) * 16) ^ ((code & 7) << 4);
    }

  for (int it = 0; it < 4; ++it) {
    __syncthreads();   // prev iter's ds_reads done before overwrite
    {
      const char* ga = abase + it * 16384 + w * 1024 + lane * 16;
      const char* gb = bbase + it * 16384 + w * 1024 + lane * 16;
      #pragma unroll
      for (int r = 0; r < 4; ++r) {
        __builtin_amdgcn_global_load_lds(
            (const __attribute__((address_space(1))) void*)(ga + r * 4096),
            (__attribute__((address_space(3))) void*)((char*)ldsA + (r * 4 + w) * 1024),
            16, 0, 0);
        __builtin_amdgcn_global_load_lds(
            (const __attribute__((address_space(1))) void*)(gb + r * 4096),
            (__attribute__((address_space(3))) void*)((char*)ldsB + (r * 4 + w) * 1024),
            16, 0, 0);
      }
    }
    __syncthreads();   // drains vmcnt(0): staged data visible
    #pragma unroll
    for (int s = 0; s < 2; ++s) {
      s8b a[4], b[4];
      #pragma unroll
      for (int m = 0; m < 4; ++m) a[m] = *(const s8b*)((const char*)ldsA + aoff[m][s]);
      #pragma unroll
      for (int n = 0; n < 4; ++n) b[n] = *(const s8b*)((const char*)ldsB + boff[n][s]);
      #pragma unroll
      for (int m = 0; m < 4; ++m)
        #pragma unroll
        for (int n = 0; n < 4; ++n)
          acc[m][n] = __builtin_amdgcn_mfma_f32_16x16x32_bf16(a[m], b[n], acc[m][n], 0, 0, 0);
    }
  }

  // epilogue: per-token max over each 32-code subtile -> subt = -2*max (fp16)
  // C frag: token-in-frag = fq*4+j, code = fr (+16*n). acc[m][n] covers
  // tokens wr*64+m*16+[0,16), codes wc*64+n*16+[0,16).
  #pragma unroll
  for (int m = 0; m < 4; ++m) {
    #pragma unroll
    for (int j = 0; j < 4; ++j) {
      float v0 = fmaxf(acc[m][0][j], acc[m][1][j]);   // codes wc*64 + [0,32)
      float v1 = fmaxf(acc[m][2][j], acc[m][3][j]);   // codes wc*64 + [32,64)
      #pragma unroll
      for (int msk = 1; msk < 16; msk <<= 1) {
        v0 = fmaxf(v0, __shfl_xor(v0, msk, 64));
        v1 = fmaxf(v1, __shfl_xor(v1, msk, 64));
      }
      if (fr == 0) {
        red[wr * 64 + m * 16 + fq * 4 + j][wc * 2 + 0] = v0;
        red[wr * 64 + m * 16 + fq * 4 + j][wc * 2 + 1] = v1;
      }
    }
  }
  __syncthreads();
  if (tid < 128) {
    const int token = ttile * 128 + tid;
    _Float16* dst = subt + (size_t)(token >> 6) * 32768 + (size_t)(token & 63) * 512
                         + (size_t)ctile * 4;
    h4 hv;
    #pragma unroll
    for (int h = 0; h < 4; ++h) hv[h] = (_Float16)(-2.0f * red[tid][h]);
    *(h4*)dst = hv;
  }
}

// ---------------- phase-2: exact re-check of candidate subtiles, argmin ----------------
__global__ __launch_bounds__(256) void k_pick(
    const float* __restrict__ z, const float* __restrict__ emb,
    const float* __restrict__ zz, const float* __restrict__ ee,
    const _Float16* __restrict__ subt, int* __restrict__ idx,
    float* __restrict__ out_idxf) {
  __shared__ float zrow[256];
  __shared__ int clist[512];
  __shared__ int ccnt;
  __shared__ float wm[4];
  __shared__ unsigned long long bests[16];
  const int n = blockIdx.x;
  const int b = n >> 10, hw = n & 1023;
  const int tid = threadIdx.x;
  const int w = tid >> 6, lane = tid & 63;
  const int g16 = lane >> 4, l16 = lane & 15;
  if (tid == 0) ccnt = 0;
  zrow[tid] = z[(size_t)b * CHW + (size_t)tid * HWD + hw];
  const _Float16* tp = subt + (size_t)(n >> 6) * 32768 + (size_t)(n & 63) * 512;
  const float ta = (float)tp[tid];
  const float tb = (float)tp[tid + 256];
  float m2 = fminf(ta, tb);
  #pragma unroll
  for (int o = 32; o; o >>= 1) m2 = fminf(m2, __shfl_xor(m2, o, 64));
  if (lane == 0) wm[w] = m2;
  __syncthreads();
  const float thr = fminf(fminf(wm[0], wm[1]), fminf(wm[2], wm[3])) + MARGIN;
  if (ta <= thr) { int p = atomicAdd(&ccnt, 1); clist[p] = tid; }
  if (tb <= thr) { int p = atomicAdd(&ccnt, 1); clist[p] = tid + 256; }
  __syncthreads();
  const int nc = ccnt;
  const float zzn = zz[n];
  unsigned long long best = ~0ull;
  for (int ci = 0; ci < nc; ++ci) {
    const int t = clist[ci];                 // candidate subtile (any order: min is total)
    #pragma unroll
    for (int p = 0; p < 2; ++p) {
      const int k = t * 32 + w * 8 + p * 4 + g16;   // 16 lanes per code
      const float* er = emb + (size_t)k * DDIM;
      double s = 0.0;
      #pragma unroll
      for (int q = 0; q < 4; ++q) {
        const float4 ev = *(const float4*)(er + q * 64 + l16 * 4);     // coalesced 256B/q
        const float4 zv = *(const float4*)(&zrow[q * 64 + l16 * 4]);   // 2-way LDS (free)
        s += (double)zv.x * (double)ev.x + (double)zv.y * (double)ev.y
           + (double)zv.z * (double)ev.z + (double)zv.w * (double)ev.w;
      }
      #pragma unroll
      for (int o = 8; o; o >>= 1) s += __shfl_xor(s, o, 16);
      if (l16 == 0) {
        const float mm = (float)s;                   // exact dot -> one fp32 rounding
        const float d = (zzn + ee[k]) - 2.0f * mm;   // replicate ref quantization (d > 0)
        const unsigned long long c =
            ((unsigned long long)__float_as_uint(d) << 32) | (unsigned int)k;
        if (c < best) best = c;                      // lexicographic (d, k): first idx wins
      }
    }
  }
  if (l16 == 0) bests[w * 4 + g16] = best;
  __syncthreads();
  if (tid == 0) {
    unsigned long long bb = bests[0];
    #pragma unroll
    for (int i = 1; i < 16; ++i) bb = bests[i] < bb ? bests[i] : bb;
    const int k0 = (int)(bb & 0xffffffffu);
    idx[n] = k0;
    out_idxf[n] = (float)k0;
  }
}

// ---------------- scatter z_q (coalesced), loss partial, counts ----------------
__global__ __launch_bounds__(256) void k_scatter(
    const float* __restrict__ z, const float* __restrict__ emb,
    const int* __restrict__ idx, float* __restrict__ out_zq,
    int* __restrict__ counts, double* __restrict__ sums) {
  __shared__ float et[64][257];   // 64 tokens x 256 dims, pad 257 (bank-free)
  __shared__ int sidx[64];
  __shared__ double w4[4];
  const int tg = blockIdx.x;      // 256 groups of 64 tokens
  const int n0 = tg * 64;
  const int b = n0 >> 10, hw0 = n0 & 1023;
  const int tid = threadIdx.x;
  if (tid < 64) sidx[tid] = idx[n0 + tid];
  __syncthreads();
  for (int i = tid; i < 16384; i += 256) {      // gather code rows (coalesced along d)
    const int t = i >> 8, d = i & 255;
    et[t][d] = emb[(size_t)sidx[t] * DDIM + d];
  }
  __syncthreads();
  const float* zb = z + (size_t)b * CHW + hw0;
  float* ob = out_zq + (size_t)b * CHW + hw0;
  double s = 0.0;
  for (int i = tid; i < 16384; i += 256) {      // NCHW order: coalesced z reads + zq writes
    const int d = i >> 6, t = i & 63;
    const float v = et[t][d];
    const float diff = v - zb[(size_t)d * HWD + t];
    ob[(size_t)d * HWD + t] = v;                // z_q_st == z_q numerically
    s += (double)diff * (double)diff;
  }
  #pragma unroll
  for (int o = 32; o; o >>= 1) s += __shfl_xor(s, o, 64);
  const int wd = tid >> 6, lane = tid & 63;
  if (lane == 0) w4[wd] = s;
  __syncthreads();
  if (tid == 0) atomicAdd(&sums[0], w4[0] + w4[1] + w4[2] + w4[3]);
  if (tid < 64) atomicAdd(&counts[sidx[tid]], 1);
}

// ---------------- entropy partial from counts ----------------
__global__ __launch_bounds__(256) void k_hist(const int* __restrict__ counts,
                                              double* __restrict__ sums) {
  const int i = blockIdx.x * 256 + threadIdx.x;
  const float em = (float)counts[i] * (1.0f / 16384.0f);
  const float term = em * logf(em + 1e-10f);
  double s = (double)term;
  #pragma unroll
  for (int o = 32; o; o >>= 1) s += __shfl_xor(s, o, 64);
  __shared__ double w4[4];
  const int wid = threadIdx.x >> 6, lane = threadIdx.x & 63;
  if (lane == 0) w4[wid] = s;
  __syncthreads();
  if (threadIdx.x == 0) atomicAdd(&sums[1], w4[0] + w4[1] + w4[2] + w4[3]);
}

// ---------------- finals ----------------
__global__ void k_final(const double* __restrict__ sums,
                        float* __restrict__ out_loss,
                        float* __restrict__ out_perp) {
  if (threadIdx.x == 0) {
    out_loss[0] = (float)(1.25 * sums[0] / 4194304.0);  // (1+BETA)*mean
    out_perp[0] = (float)exp(-sums[1]);
  }
}

extern "C" void kernel_launch(void* const* d_in, const int* in_sizes, int n_in,
                              void* d_out, int out_size, void* d_ws, size_t ws_size,
                              hipStream_t stream) {
  const float* z   = (const float*)d_in[0];   // [16,256,32,32]
  const float* emb = (const float*)d_in[1];   // [16384,256]
  float* out      = (float*)d_out;
  float* out_zq   = out;                      // 4194304
  float* out_loss = out + 4194304;
  float* out_perp = out + 4194305;
  float* out_idxf = out + 4194306;            // 16384 (idx as float)

  char* ws = (char*)d_ws;
  unsigned short* Abf = (unsigned short*)(ws + WS_ABF);
  unsigned short* Bbf = (unsigned short*)(ws + WS_BBF);
  _Float16* subt  = (_Float16*)(ws + WS_SUBT);
  float*  ee      = (float*)(ws + WS_EE);
  float*  zz      = (float*)(ws + WS_ZZ);
  int*    idx     = (int*)  (ws + WS_IDX);
  int*    counts  = (int*)  (ws + WS_CNT);
  double* sums    = (double*)(ws + WS_SUM);

  hipMemsetAsync(counts, 0, 65536 + 16, stream);

  k_cvtA <<<256, 256, 0, stream>>>(z, Abf);
  k_cvtB <<<256, 256, 0, stream>>>(emb, Bbf);
  k_mdist<<<16384, 256, 0, stream>>>(Abf, Bbf, subt);
  k_zz   <<<256, 256, 0, stream>>>(z, zz);
  k_ee   <<<256, 256, 0, stream>>>(emb, ee);
  k_pick <<<NTOK, 256, 0, stream>>>(z, emb, zz, ee, subt, idx, out_idxf);
  k_scatter<<<256, 256, 0, stream>>>(z, emb, idx, out_zq, counts, sums);
  k_hist <<<64, 256, 0, stream>>>(counts, sums);
  k_final<<<1, 64, 0, stream>>>(sums, out_loss, out_perp);
}

// Round 4
// 302.985 us; speedup vs baseline: 9.7527x; 1.3708x over previous
//
#include <hip/hip_runtime.h>
#include <math.h>

#define NTOK   16384
#define DDIM   256
#define HWD    1024        // H*W per batch image
#define CHW    262144      // 256*1024 floats per batch
#define MARGIN 1.6e-4f     // bf16 phase-1 error (8 sigma) + ref d-grid + ee span + fp16 quant

// ws layout (bytes)
#define WS_ABF   0u          // 8 MB  bf16 token images [128 tiles][4 chunks][16KB swizzled]
#define WS_BBF   8388608u    // 8 MB  bf16 code  images
#define WS_SUBT  16777216u   // 16 MB fp16 subtile mins: [n>>6][n&63][512 subtiles]
#define WS_EE    33554432u   // 64KB
#define WS_ZZ    33619968u   // 64KB
#define WS_IDX   33685504u   // 64KB
#define WS_CNT   33751040u   // 64KB
#define WS_SUM   33816576u   // 16B (contiguous after counts)

typedef __attribute__((ext_vector_type(8))) short  s8b;    // 8 bf16 (4 VGPR)
typedef __attribute__((ext_vector_type(8))) unsigned short us8;
typedef __attribute__((ext_vector_type(4))) float  f32x4;
typedef __attribute__((ext_vector_type(8))) _Float16 h8;

__device__ __forceinline__ unsigned short f2bf(float f) {
  unsigned int u = __float_as_uint(f);
  return (unsigned short)((u + 0x7fffu + ((u >> 16) & 1u)) >> 16);  // RNE
}

// ---------------- prepA: z (NCHW) -> bf16 token images + zz + zt [n][d] fp32 ----------------
// image layout per (tile,chunk): phys_byte(row,k) = ((row*128 + (k>>3)*16) ^ ((row&7)<<4)) + (k&7)*2
__global__ __launch_bounds__(256) void k_prepA(const float* __restrict__ z,
                                               unsigned short* __restrict__ Abf,
                                               float* __restrict__ zz,
                                               float* __restrict__ zt) {
  __shared__ double part[4][64];
  const int t64 = threadIdx.x & 63, chunk = threadIdx.x >> 6;
  const int n = blockIdx.x * 64 + t64;
  const int b = n >> 10, hw = n & 1023;
  const float* zp = z + (size_t)b * CHW + hw;
  const int row = n & 127, tile = n >> 7;
  char* dst = (char*)Abf + (size_t)tile * 65536 + (size_t)chunk * 16384;
  const int rowoff = row * 128, sw = (row & 7) << 4;
  float* ztp = zt + (size_t)n * 256 + chunk * 64;
  double s = 0.0;
  #pragma unroll
  for (int kb = 0; kb < 8; ++kb) {
    us8 v;
    float tmp[8];
    #pragma unroll
    for (int j = 0; j < 8; ++j) {
      const int d = chunk * 64 + kb * 8 + j;
      const float f = zp[(size_t)d * HWD];
      tmp[j] = f;
      v[j] = f2bf(f);
      s += (double)f * (double)f;                 // d ascending
    }
    *(us8*)(dst + ((rowoff + kb * 16) ^ sw)) = v;
    *(float4*)(ztp + kb * 8)     = *(float4*)&tmp[0];
    *(float4*)(ztp + kb * 8 + 4) = *(float4*)&tmp[4];
  }
  part[chunk][t64] = s;
  __syncthreads();
  if (threadIdx.x < 64)
    zz[n] = (float)(part[0][t64] + part[1][t64] + part[2][t64] + part[3][t64]);
}

// ---------------- prepB: emb -> bf16 code images + ee ----------------
__global__ __launch_bounds__(256) void k_prepB(const float* __restrict__ emb,
                                               unsigned short* __restrict__ Bbf,
                                               float* __restrict__ ee) {
  __shared__ double part[4][64];
  const int t64 = threadIdx.x & 63, chunk = threadIdx.x >> 6;
  const int code = blockIdx.x * 64 + t64;
  const float* ep = emb + (size_t)code * DDIM + chunk * 64;
  const int row = code & 127, tile = code >> 7;
  char* dst = (char*)Bbf + (size_t)tile * 65536 + (size_t)chunk * 16384;
  const int rowoff = row * 128, sw = (row & 7) << 4;
  double s = 0.0;
  #pragma unroll
  for (int kb = 0; kb < 8; ++kb) {
    const float4 f = *(const float4*)(ep + kb * 8);
    const float4 g = *(const float4*)(ep + kb * 8 + 4);
    us8 v;
    v[0] = f2bf(f.x); v[1] = f2bf(f.y); v[2] = f2bf(f.z); v[3] = f2bf(f.w);
    v[4] = f2bf(g.x); v[5] = f2bf(g.y); v[6] = f2bf(g.z); v[7] = f2bf(g.w);
    s += (double)f.x * (double)f.x; s += (double)f.y * (double)f.y;
    s += (double)f.z * (double)f.z; s += (double)f.w * (double)f.w;
    s += (double)g.x * (double)g.x; s += (double)g.y * (double)g.y;
    s += (double)g.z * (double)g.z; s += (double)g.w * (double)g.w;
    *(us8*)(dst + ((rowoff + kb * 16) ^ sw)) = v;
  }
  part[chunk][t64] = s;
  __syncthreads();
  if (threadIdx.x < 64)
    ee[code] = (float)(part[0][t64] + part[1][t64] + part[2][t64] + part[3][t64]);
}

// ---------------- phase-1: 256x256 GEMM-min, operand-swapped (A=codes, B=tokens) ----------------
// grid 4096 = 64 token-groups x 64 code-groups; 512 thr = 8 waves (2 code-halves x 4 token-qtrs).
// Wave tile: 128 codes x 64 tokens via 8x4 frags of mfma_f32_16x16x32_bf16 (A=codes -> C row=code, col=token).
// K=256 in 4 chunks of 64, 2-phase LDS double-buffer (stage issued before compute, 1 barrier/chunk).
__global__ __launch_bounds__(512, 2) void k_mdist(
    const unsigned short* __restrict__ tokimg, const unsigned short* __restrict__ codimg,
    _Float16* __restrict__ subt) {
  __shared__ __attribute__((aligned(16))) char lds[131072];   // 2 x (32KB A + 32KB B)
  const int raw = blockIdx.x;
  // XCD p owns code-groups p*8..p*8+7 (A-set 1MB, L2-fit); 8x8 (tg x cg) supertiles inside.
  const int p = raw & 7, local = raw >> 3;
  const int st = local >> 6, q = local & 63;
  const int cg = p * 8 + (q >> 3);        // 0..63: codes cg*256
  const int tg = st * 8 + (q & 7);        // 0..63: tokens tg*256
  const int tid = threadIdx.x;
  const int w = tid >> 6, lane = tid & 63;
  const int cm = w >> 2, tn = w & 3;      // code-half, token-quarter
  const int fr = lane & 15, fq = lane >> 4;

  const char* asrc = (const char*)codimg + (size_t)(2 * cg) * 65536;  // codes  (A operand)
  const char* bsrc = (const char*)tokimg + (size_t)(2 * tg) * 65536;  // tokens (B operand)

  int aoff[8][2], boff[4][2];
  #pragma unroll
  for (int m = 0; m < 8; ++m)
    #pragma unroll
    for (int ks = 0; ks < 2; ++ks) {
      const int c = cm * 128 + m * 16 + fr;
      const int rl = c & 127;
      aoff[m][ks] = (c >> 7) * 16384 + ((rl * 128 + (ks * 4 + fq) * 16) ^ ((rl & 7) << 4));
    }
  #pragma unroll
  for (int n = 0; n < 4; ++n)
    #pragma unroll
    for (int ks = 0; ks < 2; ++ks) {
      const int t = tn * 64 + n * 16 + fr;
      const int rl = t & 127;
      boff[n][ks] = 32768 + (t >> 7) * 16384 + ((rl * 128 + (ks * 4 + fq) * 16) ^ ((rl & 7) << 4));
    }

  f32x4 acc[8][4];
  #pragma unroll
  for (int m = 0; m < 8; ++m)
    #pragma unroll
    for (int n = 0; n < 4; ++n) acc[m][n] = (f32x4)0.0f;

  // stage one K-chunk (A 32KB + B 32KB) into buffer `buf`
  #define STAGE(buf, kc)                                                              \
    {                                                                                 \
      char* dstb = lds + (buf) * 65536;                                               \
      _Pragma("unroll")                                                               \
      for (int r = 0; r < 4; ++r) {                                                   \
        const int u = r * 512 + w * 64 + lane;                                        \
        const int si = u >> 10, off = (u & 1023) * 16;                                \
        __builtin_amdgcn_global_load_lds(                                             \
          (const __attribute__((address_space(1))) void*)(asrc + (size_t)si * 65536 + (kc) * 16384 + off), \
          (__attribute__((address_space(3))) void*)(dstb + u * 16), 16, 0, 0);        \
      }                                                                               \
      _Pragma("unroll")                                                               \
      for (int r = 0; r < 4; ++r) {                                                   \
        const int u = r * 512 + w * 64 + lane;                                        \
        const int si = u >> 10, off = (u & 1023) * 16;                                \
        __builtin_amdgcn_global_load_lds(                                             \
          (const __attribute__((address_space(1))) void*)(bsrc + (size_t)si * 65536 + (kc) * 16384 + off), \
          (__attribute__((address_space(3))) void*)(dstb + 32768 + u * 16), 16, 0, 0); \
      }                                                                               \
    }

  STAGE(0, 0);
  __syncthreads();                          // vmcnt(0) drain: buf0 ready
  #pragma unroll
  for (int kc = 0; kc < 4; ++kc) {
    if (kc < 3) STAGE((kc + 1) & 1, kc + 1);     // issue next chunk BEFORE compute
    const char* bufb = lds + (kc & 1) * 65536;
    #pragma unroll
    for (int ks = 0; ks < 2; ++ks) {
      s8b a[8], bf[4];
      #pragma unroll
      for (int m = 0; m < 8; ++m) a[m] = *(const s8b*)(bufb + aoff[m][ks]);
      #pragma unroll
      for (int n = 0; n < 4; ++n) bf[n] = *(const s8b*)(bufb + boff[n][ks]);
      #pragma unroll
      for (int m = 0; m < 8; ++m)
        #pragma unroll
        for (int n = 0; n < 4; ++n)
          acc[m][n] = __builtin_amdgcn_mfma_f32_16x16x32_bf16(a[m], bf[n], acc[m][n], 0, 0, 0);
    }
    __syncthreads();                        // one drain per chunk (loads had full compute to land)
  }

  // epilogue: per-token max per 32-code subtile (codes on reg+fq axis -> cheap)
  _Float16* outT = (_Float16*)lds;          // [256 tokens][8 subtiles], aliases buf0 (dead)
  #pragma unroll
  for (int s = 0; s < 4; ++s) {
    #pragma unroll
    for (int n = 0; n < 4; ++n) {
      float v = acc[2 * s][n][0];
      #pragma unroll
      for (int j = 1; j < 4; ++j) v = fmaxf(v, acc[2 * s][n][j]);
      #pragma unroll
      for (int j = 0; j < 4; ++j) v = fmaxf(v, acc[2 * s + 1][n][j]);
      v = fmaxf(v, __shfl_xor(v, 16, 64));  // fold fq bit0
      v = fmaxf(v, __shfl_xor(v, 32, 64));  // fold fq bit1 -> max over all 32 codes
      if (lane < 16)
        outT[(tn * 64 + n * 16 + fr) * 8 + cm * 4 + s] = (_Float16)(-2.0f * v);
    }
  }
  __syncthreads();
  if (tid < 256) {
    const int t = tid;                      // token n = tg*256 + t
    _Float16* g = subt + (size_t)(tg * 4 + (t >> 6)) * 32768 + (size_t)(t & 63) * 512 + cg * 8;
    *(h8*)g = *(const h8*)(outT + t * 8);
  }
}

// ---------------- phase-2: exact re-check of candidate subtiles, argmin ----------------
__global__ __launch_bounds__(256) void k_pick(
    const float* __restrict__ zt, const float* __restrict__ emb,
    const float* __restrict__ zz, const float* __restrict__ ee,
    const _Float16* __restrict__ subt, int* __restrict__ idx,
    float* __restrict__ out_idxf) {
  __shared__ float zrow[256];
  __shared__ int clist[512];
  __shared__ int ccnt;
  __shared__ float wm[4];
  __shared__ unsigned long long bests[16];
  const int n = blockIdx.x;
  const int tid = threadIdx.x;
  const int w = tid >> 6, lane = tid & 63;
  const int g16 = lane >> 4, l16 = lane & 15;
  if (tid == 0) ccnt = 0;
  zrow[tid] = zt[(size_t)n * 256 + tid];          // coalesced row
  const _Float16* tp = subt + (size_t)(n >> 6) * 32768 + (size_t)(n & 63) * 512;
  const float ta = (float)tp[tid];
  const float tb = (float)tp[tid + 256];
  float m2 = fminf(ta, tb);
  #pragma unroll
  for (int o = 32; o; o >>= 1) m2 = fminf(m2, __shfl_xor(m2, o, 64));
  if (lane == 0) wm[w] = m2;
  __syncthreads();
  const float thr = fminf(fminf(wm[0], wm[1]), fminf(wm[2], wm[3])) + MARGIN;
  if (ta <= thr) { int p = atomicAdd(&ccnt, 1); clist[p] = tid; }
  if (tb <= thr) { int p = atomicAdd(&ccnt, 1); clist[p] = tid + 256; }
  __syncthreads();
  const int nc = ccnt;
  const float zzn = zz[n];
  unsigned long long best = ~0ull;
  for (int ci = 0; ci < nc; ++ci) {
    const int t = clist[ci];                 // candidate subtile (any order: min is total)
    #pragma unroll
    for (int p = 0; p < 2; ++p) {
      const int k = t * 32 + w * 8 + p * 4 + g16;   // 16 lanes per code
      const float* er = emb + (size_t)k * DDIM;
      double s = 0.0;
      #pragma unroll
      for (int q = 0; q < 4; ++q) {
        const float4 ev = *(const float4*)(er + q * 64 + l16 * 4);     // coalesced 256B/q
        const float4 zv = *(const float4*)(&zrow[q * 64 + l16 * 4]);
        s += (double)zv.x * (double)ev.x + (double)zv.y * (double)ev.y
           + (double)zv.z * (double)ev.z + (double)zv.w * (double)ev.w;
      }
      #pragma unroll
      for (int o = 8; o; o >>= 1) s += __shfl_xor(s, o, 16);
      if (l16 == 0) {
        const float mm = (float)s;                   // exact dot -> one fp32 rounding
        const float d = (zzn + ee[k]) - 2.0f * mm;   // replicate ref quantization (d > 0)
        const unsigned long long c =
            ((unsigned long long)__float_as_uint(d) << 32) | (unsigned int)k;
        if (c < best) best = c;                      // lexicographic (d, k): first idx wins
      }
    }
  }
  if (l16 == 0) bests[w * 4 + g16] = best;
  __syncthreads();
  if (tid == 0) {
    unsigned long long bb = bests[0];
    #pragma unroll
    for (int i = 1; i < 16; ++i) bb = bests[i] < bb ? bests[i] : bb;
    const int k0 = (int)(bb & 0xffffffffu);
    idx[n] = k0;
    out_idxf[n] = (float)k0;
  }
}

// ---------------- scatter z_q (coalesced), loss partial, counts ----------------
__global__ __launch_bounds__(256) void k_scatter(
    const float* __restrict__ z, const float* __restrict__ emb,
    const int* __restrict__ idx, float* __restrict__ out_zq,
    int* __restrict__ counts, double* __restrict__ sums) {
  __shared__ float et[64][257];   // 64 tokens x 256 dims, pad 257
  __shared__ int sidx[64];
  __shared__ double w4[4];
  const int tg = blockIdx.x;      // 256 groups of 64 tokens
  const int n0 = tg * 64;
  const int b = n0 >> 10, hw0 = n0 & 1023;
  const int tid = threadIdx.x;
  if (tid < 64) sidx[tid] = idx[n0 + tid];
  __syncthreads();
  for (int i = tid; i < 16384; i += 256) {      // gather code rows (coalesced along d)
    const int t = i >> 8, d = i & 255;
    et[t][d] = emb[(size_t)sidx[t] * DDIM + d];
  }
  __syncthreads();
  const float* zb = z + (size_t)b * CHW + hw0;
  float* ob = out_zq + (size_t)b * CHW + hw0;
  double s = 0.0;
  for (int i = tid; i < 16384; i += 256) {      // NCHW order: coalesced z reads + zq writes
    const int d = i >> 6, t = i & 63;
    const float v = et[t][d];
    const float diff = v - zb[(size_t)d * HWD + t];
    ob[(size_t)d * HWD + t] = v;                // z_q_st == z_q numerically
    s += (double)diff * (double)diff;
  }
  #pragma unroll
  for (int o = 32; o; o >>= 1) s += __shfl_xor(s, o, 64);
  const int wd = tid >> 6, lane = tid & 63;
  if (lane == 0) w4[wd] = s;
  __syncthreads();
  if (tid == 0) atomicAdd(&sums[0], w4[0] + w4[1] + w4[2] + w4[3]);
  if (tid < 64) atomicAdd(&counts[sidx[tid]], 1);
}

// ---------------- entropy partial from counts ----------------
__global__ __launch_bounds__(256) void k_hist(const int* __restrict__ counts,
                                              double* __restrict__ sums) {
  const int i = blockIdx.x * 256 + threadIdx.x;
  const float em = (float)counts[i] * (1.0f / 16384.0f);
  const float term = em * logf(em + 1e-10f);
  double s = (double)term;
  #pragma unroll
  for (int o = 32; o; o >>= 1) s += __shfl_xor(s, o, 64);
  __shared__ double w4[4];
  const int wid = threadIdx.x >> 6, lane = threadIdx.x & 63;
  if (lane == 0) w4[wid] = s;
  __syncthreads();
  if (threadIdx.x == 0) atomicAdd(&sums[1], w4[0] + w4[1] + w4[2] + w4[3]);
}

// ---------------- finals ----------------
__global__ void k_final(const double* __restrict__ sums,
                        float* __restrict__ out_loss,
                        float* __restrict__ out_perp) {
  if (threadIdx.x == 0) {
    out_loss[0] = (float)(1.25 * sums[0] / 4194304.0);  // (1+BETA)*mean
    out_perp[0] = (float)exp(-sums[1]);
  }
}

extern "C" void kernel_launch(void* const* d_in, const int* in_sizes, int n_in,
                              void* d_out, int out_size, void* d_ws, size_t ws_size,
                              hipStream_t stream) {
  const float* z   = (const float*)d_in[0];   // [16,256,32,32]
  const float* emb = (const float*)d_in[1];   // [16384,256]
  float* out      = (float*)d_out;
  float* out_zq   = out;                      // 4194304
  float* out_loss = out + 4194304;
  float* out_perp = out + 4194305;
  float* out_idxf = out + 4194306;            // 16384 (idx as float)
  float* zt       = out;                      // [n][d] fp32 transpose; dead before k_scatter overwrites

  char* ws = (char*)d_ws;
  unsigned short* Abf = (unsigned short*)(ws + WS_ABF);
  unsigned short* Bbf = (unsigned short*)(ws + WS_BBF);
  _Float16* subt  = (_Float16*)(ws + WS_SUBT);
  float*  ee      = (float*)(ws + WS_EE);
  float*  zz      = (float*)(ws + WS_ZZ);
  int*    idx     = (int*)  (ws + WS_IDX);
  int*    counts  = (int*)  (ws + WS_CNT);
  double* sums    = (double*)(ws + WS_SUM);

  hipMemsetAsync(counts, 0, 65536 + 16, stream);

  k_prepA<<<256, 256, 0, stream>>>(z, Abf, zz, zt);
  k_prepB<<<256, 256, 0, stream>>>(emb, Bbf, ee);
  k_mdist<<<4096, 512, 0, stream>>>(Abf, Bbf, subt);
  k_pick <<<NTOK, 256, 0, stream>>>(zt, emb, zz, ee, subt, idx, out_idxf);
  k_scatter<<<256, 256, 0, stream>>>(z, emb, idx, out_zq, counts, sums);
  k_hist <<<64, 256, 0, stream>>>(counts, sums);
  k_final<<<1, 64, 0, stream>>>(sums, out_loss, out_perp);
}